// Round 8
// baseline (309.357 us; speedup 1.0000x reference)
//
#include <hip/hip_runtime.h>

// GestureRNN v16: v15 MFMA core at 4 WAVES/CU (4 batches/wave, columns
// duplicated 4x). B=4096, T=512, IN=10, H=32, NCLS=9.
//
// v13/v14/v15 post-mortem: three dependency-structure rewrites all flat at
// ~199-220us. At 2.4GHz: 932 cyc/step with MfmaUtil 5% (60 cyc MFMA) and
// VALUBusy 12% (114 cyc VALU) exactly matching the instruction stream =>
// ~780 cyc/step STALL, insensitive to ILP. v9 (4 waves/CU) sustained 82%
// issue => co-resident waves DO hide this machine's latencies. v12-15 run
// 1 wave/CU (occ 2.9%) because 4096/16 batches = 256 waves exactly. v16
// buys TLP with MFMA column waste: each wave handles 4 real batches
// (B/C columns c, c+4, c+8, c+12 duplicate batch blk*4+(c&3)), grid 1024
// blocks = 4 waves/CU. Per-wave instruction stream identical to v15;
// duplicate x loads coalesce (4 lanes, same address). LDS XP_ 20->12
// (25.6 KB/block) so 4 blocks co-reside. Output stores guarded to c<4.
// Layout conjugation K(k)=16*((k>>2)&1)+4*(k>>3)+(k&3) HW-verified (v12+).

constexpr int T_  = 512;
constexpr int IN_ = 10;
constexpr int H_  = 32;
constexpr int NC_ = 9;
constexpr int CT_ = 16;        // timesteps per chunk
constexpr int NCH = T_ / CT_;  // 32 chunks
constexpr int XP_ = 12;        // floats per (slot,lane) in xlds (48 B slots)

typedef _Float16 f16x8 __attribute__((ext_vector_type(8)));
typedef float    f32x4 __attribute__((ext_vector_type(4)));

__device__ __forceinline__ void cfence() { __asm__ volatile("" ::: "memory"); }

__device__ __forceinline__ f32x4 MFMA(f16x8 a, f16x8 b, f32x4 c) {
    return __builtin_amdgcn_mfma_f32_16x16x32_f16(a, b, c, 0, 0, 0);
}

__global__ __launch_bounds__(64, 1)
void gesture_rnn_kernel(
    const float* __restrict__ x,      // [B, T, IN]
    const float* __restrict__ W_ih0,  // [H, IN]
    const float* __restrict__ W_hh0,  // [H, H]
    const float* __restrict__ b_ih0,  // [H]
    const float* __restrict__ b_hh0,  // [H]
    const float* __restrict__ W_ih1,  // [H, H]
    const float* __restrict__ W_hh1,  // [H, H]
    const float* __restrict__ b_ih1,  // [H]
    const float* __restrict__ b_hh1,  // [H]
    const float* __restrict__ W_fc,   // [NC, H]
    const float* __restrict__ b_fc,   // [NC]
    float* __restrict__ out)          // [B, NC]
{
    const int lane = threadIdx.x;     // 0..63
    const int c    = lane & 15;       // B/C column; batch = blk*4 + (c&3)
    const int g    = lane >> 4;       // k-group (A/B), C row-group: 0..3
    const long b   = (long)blockIdx.x * 4 + (c & 3);   // 4x duplicated cols

    // ---- A-fragments. Lane l: row = l&15, k = (l>>4)*8 + j.
    //      Recurrent matrices use k-order K(k); xproj uses natural k. ----
    f16x8 ah0[2], ai1[2], ah1[2], axh[2], axl[2];
#pragma unroll
    for (int Tt = 0; Tt < 2; ++Tt) {
#pragma unroll
        for (int j = 0; j < 8; ++j) {
            const int k   = 8 * g + j;
            const int kp  = 16 * ((k >> 2) & 1) + 4 * (k >> 3) + (k & 3);
            const int row = 16 * Tt + c;
            ah0[Tt][j] = (_Float16)W_hh0[row * H_ + kp];
            ai1[Tt][j] = (_Float16)W_ih1[row * H_ + kp];
            ah1[Tt][j] = (_Float16)W_hh1[row * H_ + kp];
            const float wx = (k < IN_) ? W_ih0[row * IN_ + k] : 0.f;
            const _Float16 wh = (_Float16)wx;
            axh[Tt][j] = wh;
            axl[Tt][j] = (_Float16)(wx - (float)wh);   // residual for f32 accuracy
        }
    }
    // ---- bias C-inits (C layout: lane(g,c) reg r = unit 16T+4g+r) ----
    f32x4 b0i[2], b1i[2];
#pragma unroll
    for (int Tt = 0; Tt < 2; ++Tt)
#pragma unroll
        for (int r = 0; r < 4; ++r) {
            const int uu = 16 * Tt + 4 * g + r;
            b0i[Tt][r] = b_ih0[uu] + b_hh0[uu];
            b1i[Tt][r] = b_ih1[uu] + b_hh1[uu];
        }
    const f32x4 zf4 = {0.f, 0.f, 0.f, 0.f};

    __shared__ float xlds[2][4 * 64 * XP_];  // double-buffered x staging
    __shared__ _Float16 hfin[16][H_];        // final h2 for FC head

    // ---- x staging: lane(g,c) owns timesteps 4g+s (s=0..3) of batch b.
    //      Lanes c, c+4, c+8, c+12 load the SAME addresses (coalesced). ----
    float xr[4][IN_];
    const float* xg = x + ((size_t)b * T_ + 4 * g) * IN_;
#pragma unroll
    for (int s = 0; s < 4; ++s)
#pragma unroll
        for (int i = 0; i < IN_; i += 2) {
            const float2 v = *(const float2*)(xg + s * IN_ + i);
            xr[s][i] = v.x; xr[s][i + 1] = v.y;
        }
    xg += CT_ * IN_;

    f16x8 h1f, h2f;
#pragma unroll
    for (int j = 0; j < 8; ++j) { h1f[j] = (_Float16)0.f; h2f[j] = (_Float16)0.f; }

    f32x4 xpA0, xpA1, xpB0, xpB1;   // depth-2 xproj pipeline (16 VGPRs)

    // ---- DUMP(BASE, PREFETCH): x regs -> LDS buffer; prefetch next chunk ----
#define DUMP(BASE, PREFETCH)                                                 \
    {                                                                        \
        _Pragma("unroll")                                                    \
        for (int s_ = 0; s_ < 4; ++s_) {                                     \
            float* dst_ = (BASE) + (s_ * 64 + lane) * XP_;                   \
            *(float4*)(dst_)     = make_float4(xr[s_][0], xr[s_][1],         \
                                               xr[s_][2], xr[s_][3]);        \
            *(float4*)(dst_ + 4) = make_float4(xr[s_][4], xr[s_][5],         \
                                               xr[s_][6], xr[s_][7]);        \
            *(float2*)(dst_ + 8) = make_float2(xr[s_][8], xr[s_][9]);        \
        }                                                                    \
        if (PREFETCH) {                                                      \
            _Pragma("unroll")                                                \
            for (int s_ = 0; s_ < 4; ++s_)                                   \
                _Pragma("unroll")                                            \
                for (int i_ = 0; i_ < IN_; i_ += 2) {                        \
                    const float2 v_ = *(const float2*)(xg + s_ * IN_ + i_);  \
                    xr[s_][i_] = v_.x; xr[s_][i_ + 1] = v_.y;                \
                }                                                            \
            xg += CT_ * IN_;                                                 \
        }                                                                    \
        cfence();                                                            \
    }

    // ---- XPROJ(BASE, TT, P0, P1): xp = W_ih0 @ x[TT] + b0 (f32 split) ----
#define XPROJ(BASE, TT, P0, P1)                                              \
    {                                                                        \
        const float* rp_ = (BASE) +                                          \
            ((((TT) & 3) * 64 + ((TT) >> 2) * 16 + c) * XP_);                \
        f16x8 bxh_, bxl_;                                                    \
        _Pragma("unroll")                                                    \
        for (int j_ = 0; j_ < 8; ++j_) {                                     \
            bxh_[j_] = (_Float16)0.f; bxl_[j_] = (_Float16)0.f;              \
        }                                                                    \
        if (g == 0) {                                                        \
            const float4 v0_ = *(const float4*)rp_;                          \
            const float4 v1_ = *(const float4*)(rp_ + 4);                    \
            const float xv_[8] = {v0_.x, v0_.y, v0_.z, v0_.w,                \
                                  v1_.x, v1_.y, v1_.z, v1_.w};               \
            _Pragma("unroll")                                                \
            for (int j_ = 0; j_ < 8; ++j_) {                                 \
                const _Float16 hh_ = (_Float16)xv_[j_];                      \
                bxh_[j_] = hh_;                                              \
                bxl_[j_] = (_Float16)(xv_[j_] - (float)hh_);                 \
            }                                                                \
        } else if (g == 1) {                                                 \
            const float2 v2_ = *(const float2*)(rp_ + 8);                    \
            const _Float16 ha_ = (_Float16)v2_.x;                            \
            bxh_[0] = ha_; bxl_[0] = (_Float16)(v2_.x - (float)ha_);         \
            const _Float16 hb_ = (_Float16)v2_.y;                            \
            bxh_[1] = hb_; bxl_[1] = (_Float16)(v2_.y - (float)hb_);         \
        }                                                                    \
        P0 = MFMA(axh[0], bxh_, b0i[0]);                                     \
        P1 = MFMA(axh[1], bxh_, b0i[1]);                                     \
        P0 = MFMA(axh[0], bxl_, P0);                                         \
        P1 = MFMA(axh[1], bxl_, P1);                                         \
        P0 = MFMA(axl[0], bxh_, P0);                                         \
        P1 = MFMA(axl[1], bxh_, P1);                                         \
    }

    // ---- STEPP: consumes xpA (= xp(tau)); computes xp(tau+2) into the
    //      pipeline. Invariant on entry: xpA=xp(tau), xpB=xp(tau+1). ----
#define STEPP(RR, DOX, XBASE)                                                \
    {                                                                        \
        const f32x4 c0_ = MFMA(ah0[0], h1f, xpA0);                           \
        const f32x4 c1_ = MFMA(ah0[1], h1f, xpA1);                           \
        const f32x4 d0_ = MFMA(ai1[0], h1f, b1i[0]);                         \
        const f32x4 d1_ = MFMA(ai1[1], h1f, b1i[1]);                         \
        const f32x4 e0_ = MFMA(ah1[0], h2f, zf4);                            \
        const f32x4 e1_ = MFMA(ah1[1], h2f, zf4);                            \
        f32x4 q0_, q1_;                                                      \
        if (DOX) { XPROJ(XBASE, (((RR) + 2) & 15), q0_, q1_) }               \
        f16x8 nh1_, nh2_;                                                    \
        _Pragma("unroll")                                                    \
        for (int r_ = 0; r_ < 4; ++r_) {                                     \
            nh1_[r_]     = (_Float16)fmaxf(c0_[r_], 0.f);                    \
            nh1_[4 + r_] = (_Float16)fmaxf(c1_[r_], 0.f);                    \
            nh2_[r_]     = (_Float16)fmaxf(d0_[r_] + e0_[r_], 0.f);          \
            nh2_[4 + r_] = (_Float16)fmaxf(d1_[r_] + e1_[r_], 0.f);          \
        }                                                                    \
        h1f = nh1_; h2f = nh2_;                                              \
        xpA0 = xpB0; xpA1 = xpB1;                                            \
        if (DOX) { xpB0 = q0_; xpB1 = q1_; }                                 \
    }

    float* bufA = &xlds[0][0];
    float* bufB = &xlds[1][0];

    // ---- chunk 0 prologue: stage chunk0, prefetch chunk1, fill pipeline ----
    DUMP(bufA, 1);
    XPROJ(bufA, 0, xpA0, xpA1);
    XPROJ(bufA, 1, xpB0, xpB1);
    {
        // tau=0: h1[0] = relu(xp(0)); h2[-1] = 0. Advance pipeline.
        f16x8 nh1;
#pragma unroll
        for (int r = 0; r < 4; ++r) {
            nh1[r]     = (_Float16)fmaxf(xpA0[r], 0.f);
            nh1[4 + r] = (_Float16)fmaxf(xpA1[r], 0.f);
        }
        h1f = nh1;   // h2f stays 0
        xpA0 = xpB0; xpA1 = xpB1;
        XPROJ(bufA, 2, xpB0, xpB1);
    }
    // ---- chunk 0 steps 1..15 (mid-chunk: stage chunk1 -> bufB) ----
#pragma unroll
    for (int r = 1; r < 8; ++r) STEPP(r, 1, bufA);
    DUMP(bufB, 1);   // stage chunk1, prefetch chunk2
#pragma unroll
    for (int r = 8; r < 14; ++r) STEPP(r, 1, bufA);
    STEPP(14, 1, bufB);   // XPROJ t=0 of chunk1
    STEPP(15, 1, bufB);   // XPROJ t=1 of chunk1

    // ---- chunks 1..30 ----
    float* cur = bufB;
    float* nxt = bufA;
#pragma unroll 1
    for (int n = 1; n <= 30; ++n) {
#pragma unroll
        for (int r = 0; r < 8; ++r) STEPP(r, 1, cur);
        DUMP(nxt, (n < 30));   // stage chunk n+1, prefetch chunk n+2
#pragma unroll
        for (int r = 8; r < 14; ++r) STEPP(r, 1, cur);
        STEPP(14, 1, nxt);
        STEPP(15, 1, nxt);
        float* tmp = cur; cur = nxt; nxt = tmp;
    }

    // ---- chunk 31 (no staging, no next-chunk XPROJ) ----
#pragma unroll
    for (int r = 0; r < 14; ++r) STEPP(r, 1, cur);
    STEPP(14, 0, cur);
    STEPP(15, 0, cur);

    // ---- epilogue: h2[511] = relu(b1 + W_ih1.h1[511] + W_hh1.h2[510]) ----
    {
        const f32x4 d0 = MFMA(ai1[0], h1f, b1i[0]);
        const f32x4 d1 = MFMA(ai1[1], h1f, b1i[1]);
        const f32x4 e0 = MFMA(ah1[0], h2f, zf4);
        const f32x4 e1 = MFMA(ah1[1], h2f, zf4);
        f16x8 nh2;
#pragma unroll
        for (int r = 0; r < 4; ++r) {
            nh2[r]     = (_Float16)fmaxf(d0[r] + e0[r], 0.f);
            nh2[4 + r] = (_Float16)fmaxf(d1[r] + e1[r], 0.f);
        }
        h2f = nh2;
    }

    // ---- FC head: h2f C-layout -> hfin[c][unit], then 2-3 classes/lane.
    //      Only columns c<4 are distinct batches; guard the stores. ----
#pragma unroll
    for (int r = 0; r < 4; ++r) {
        hfin[c][4 * g + r]      = h2f[r];
        hfin[c][16 + 4 * g + r] = h2f[4 + r];
    }
    cfence();   // single-wave in-order DS pipe: writes precede reads
    if (c < 4) {
        float acc0 = b_fc[g];
        float acc1 = b_fc[g + 4];
        float acc2 = (g == 0) ? b_fc[8] : 0.f;
#pragma unroll
        for (int k = 0; k < H_; ++k) {
            const float hv = (float)hfin[c][k];
            acc0 = fmaf(W_fc[g * H_ + k], hv, acc0);
            acc1 = fmaf(W_fc[(g + 4) * H_ + k], hv, acc1);
            if (g == 0) acc2 = fmaf(W_fc[8 * H_ + k], hv, acc2);
        }
        out[b * NC_ + g]     = acc0;
        out[b * NC_ + g + 4] = acc1;
        if (g == 0) out[b * NC_ + 8] = acc2;
    }
#undef DUMP
#undef XPROJ
#undef STEPP
}

extern "C" void kernel_launch(void* const* d_in, const int* in_sizes, int n_in,
                              void* d_out, int out_size, void* d_ws, size_t ws_size,
                              hipStream_t stream) {
    const float* x     = (const float*)d_in[0];
    const float* W_ih0 = (const float*)d_in[1];
    const float* W_hh0 = (const float*)d_in[2];
    const float* b_ih0 = (const float*)d_in[3];
    const float* b_hh0 = (const float*)d_in[4];
    const float* W_ih1 = (const float*)d_in[5];
    const float* W_hh1 = (const float*)d_in[6];
    const float* b_ih1 = (const float*)d_in[7];
    const float* b_hh1 = (const float*)d_in[8];
    const float* W_fc  = (const float*)d_in[9];
    const float* b_fc  = (const float*)d_in[10];
    float* out = (float*)d_out;

    const int B = in_sizes[0] / (T_ * IN_);   // 4096
    gesture_rnn_kernel<<<dim3(B / 4), dim3(64), 0, stream>>>(
        x, W_ih0, W_hh0, b_ih0, b_hh0, W_ih1, W_hh1, b_ih1, b_hh1,
        W_fc, b_fc, out);
}

// Round 9
// 217.580 us; speedup vs baseline: 1.4218x; 1.4218x over previous
//
#include <hip/hip_runtime.h>

// GestureRNN v17: MFMA recurrence with a VALU-starved step.
// B=4096, T=512, IN=10, H=32, NCLS=9.
//
// v16 post-mortem (215us, occ 11.3%, MfmaUtil 19.4%, VALUBusy 47.7%): 4
// waves/CU overlap perfectly but wall time unchanged => wall = 512 x
// per-step-time of the serial chain; TLP can't shorten it. Per-SIMD busy
// shows ~440 cyc VALU issue/step (~150-220 glue ops: f32->f16 split unpack,
// cvt/pack, pipeline movs, divergent branches) + ~80 MFMA + ~400 exposure.
// v17 strips the glue: (1) x pre-converted to packed-f16 hi/lo B-fragments
// at DUMP (amortized ~9 op/step) -> XPROJ = 2 ds_read_b128 + 6 MFMA, zero
// unpack; (2) parity-unrolled depth-2 xp pipeline (xpE/xpO regenerated in
// place, no movs); (3) h2 adds folded into MFMA accumulate chain (full-rate
// same-acc back-to-back, the GEMM K-loop pattern); (4) g>=2 lanes read a
// 16B zero slot (broadcast). Step ~= 12 MFMA + ~45 VALU + 2 ds_read.
// Layout conjugation K(k)=16*((k>>2)&1)+4*(k>>3)+(k&3) HW-verified (v12+).
// 256 blocks x 1 wave (16 real batches/wave; v16 proved duplication buys
// nothing and costs contention).

constexpr int T_  = 512;
constexpr int IN_ = 10;
constexpr int H_  = 32;
constexpr int NC_ = 9;
constexpr int CT_ = 16;        // timesteps per chunk
constexpr int NCH = T_ / CT_;  // 32 chunks

typedef _Float16 f16x8 __attribute__((ext_vector_type(8)));
typedef _Float16 h2t  __attribute__((ext_vector_type(2)));
typedef float    f32x4 __attribute__((ext_vector_type(4)));

__device__ __forceinline__ void cfence() { __asm__ volatile("" ::: "memory"); }

__device__ __forceinline__ f32x4 MFMA(f16x8 a, f16x8 b, f32x4 c) {
    return __builtin_amdgcn_mfma_f32_16x16x32_f16(a, b, c, 0, 0, 0);
}

__global__ __launch_bounds__(64, 1)
__attribute__((amdgpu_waves_per_eu(1, 1)))
void gesture_rnn_kernel(
    const float* __restrict__ x,      // [B, T, IN]
    const float* __restrict__ W_ih0,  // [H, IN]
    const float* __restrict__ W_hh0,  // [H, H]
    const float* __restrict__ b_ih0,  // [H]
    const float* __restrict__ b_hh0,  // [H]
    const float* __restrict__ W_ih1,  // [H, H]
    const float* __restrict__ W_hh1,  // [H, H]
    const float* __restrict__ b_ih1,  // [H]
    const float* __restrict__ b_hh1,  // [H]
    const float* __restrict__ W_fc,   // [NC, H]
    const float* __restrict__ b_fc,   // [NC]
    float* __restrict__ out)          // [B, NC]
{
    const int lane = threadIdx.x;     // 0..63
    const int c    = lane & 15;       // batch col (B/C col, A row)
    const int g    = lane >> 4;       // k-group: holds k = 8g..8g+7
    const long b   = (long)blockIdx.x * 16 + c;

    // ---- A-fragments (k-order K(k) for recurrent mats; natural for xproj) --
    f16x8 ah0[2], ai1[2], ah1[2], axh[2], axl[2];
#pragma unroll
    for (int Tt = 0; Tt < 2; ++Tt) {
#pragma unroll
        for (int j = 0; j < 8; ++j) {
            const int k   = 8 * g + j;
            const int kp  = 16 * ((k >> 2) & 1) + 4 * (k >> 3) + (k & 3);
            const int row = 16 * Tt + c;
            ah0[Tt][j] = (_Float16)W_hh0[row * H_ + kp];
            ai1[Tt][j] = (_Float16)W_ih1[row * H_ + kp];
            ah1[Tt][j] = (_Float16)W_hh1[row * H_ + kp];
            const float wx = (k < IN_) ? W_ih0[row * IN_ + k] : 0.f;
            const _Float16 wh = (_Float16)wx;
            axh[Tt][j] = wh;
            axl[Tt][j] = (_Float16)(wx - (float)wh);
        }
    }
    f32x4 b0i[2], b1i[2];
#pragma unroll
    for (int Tt = 0; Tt < 2; ++Tt)
#pragma unroll
        for (int r = 0; r < 4; ++r) {
            const int uu = 16 * Tt + 4 * g + r;
            b0i[Tt][r] = b_ih0[uu] + b_hh0[uu];
            b1i[Tt][r] = b_ih1[uu] + b_hh1[uu];
        }

    // ---- LDS: packed-f16 x B-fragments, double-buffered ----
    __shared__ uint4 xhl[2][2][CT_][2][16];  // [buf][hi/lo][t][g01][c]
    __shared__ uint4 zs4;                    // zero frag for g>=2 lanes
    __shared__ _Float16 hfin[16][H_];

    if (lane == 0) zs4 = make_uint4(0u, 0u, 0u, 0u);

    // ---- x load: lane(g,c) owns timesteps 4g+s (s=0..3) of batch b ----
    float xr[4][IN_];
    const float* xg = x + ((size_t)b * T_ + 4 * g) * IN_;
#pragma unroll
    for (int s = 0; s < 4; ++s)
#pragma unroll
        for (int i = 0; i < IN_; i += 2) {
            const float2 v = *(const float2*)(xg + s * IN_ + i);
            xr[s][i] = v.x; xr[s][i + 1] = v.y;
        }
    xg += CT_ * IN_;

    // per-lane read pointers: g<2 reads its fragment slice, g>=2 the zero slot
    const int tmul = (g < 2) ? 32 : 0;       // uint4 stride per t
    const uint4* hpA = (g < 2) ? &xhl[0][0][0][g][c] : &zs4;
    const uint4* lpA = (g < 2) ? &xhl[0][1][0][g][c] : &zs4;
    const uint4* hpB = (g < 2) ? &xhl[1][0][0][g][c] : &zs4;
    const uint4* lpB = (g < 2) ? &xhl[1][1][0][g][c] : &zs4;

    f16x8 h1f, h2f;
#pragma unroll
    for (int j = 0; j < 8; ++j) { h1f[j] = (_Float16)0.f; h2f[j] = (_Float16)0.f; }

    f32x4 xpE0, xpE1, xpO0, xpO1;   // parity-held xp pipeline (no movs)

    // ---- DUMP(BUF, PREFETCH): convert xr -> packed f16 hi/lo frags in LDS --
#define DUMP(BUF, PREFETCH)                                                  \
    {                                                                        \
        _Pragma("unroll")                                                    \
        for (int s_ = 0; s_ < 4; ++s_) {                                     \
            const int t_ = 4 * g + s_;                                       \
            unsigned int hd_[5], ld_[5];                                     \
            _Pragma("unroll")                                                \
            for (int p_ = 0; p_ < 5; ++p_) {                                 \
                const float a_ = xr[s_][2 * p_], q_ = xr[s_][2 * p_ + 1];    \
                const _Float16 ha_ = (_Float16)a_, hb_ = (_Float16)q_;       \
                h2t hh_; hh_[0] = ha_; hh_[1] = hb_;                         \
                hd_[p_] = __builtin_bit_cast(unsigned int, hh_);             \
                h2t ll_; ll_[0] = (_Float16)(a_ - (float)ha_);               \
                ll_[1] = (_Float16)(q_ - (float)hb_);                        \
                ld_[p_] = __builtin_bit_cast(unsigned int, ll_);             \
            }                                                                \
            xhl[BUF][0][t_][0][c] = make_uint4(hd_[0], hd_[1], hd_[2], hd_[3]); \
            xhl[BUF][0][t_][1][c] = make_uint4(hd_[4], 0u, 0u, 0u);          \
            xhl[BUF][1][t_][0][c] = make_uint4(ld_[0], ld_[1], ld_[2], ld_[3]); \
            xhl[BUF][1][t_][1][c] = make_uint4(ld_[4], 0u, 0u, 0u);          \
        }                                                                    \
        if (PREFETCH) {                                                      \
            _Pragma("unroll")                                                \
            for (int s_ = 0; s_ < 4; ++s_)                                   \
                _Pragma("unroll")                                            \
                for (int i_ = 0; i_ < IN_; i_ += 2) {                        \
                    const float2 v_ = *(const float2*)(xg + s_ * IN_ + i_);  \
                    xr[s_][i_] = v_.x; xr[s_][i_ + 1] = v_.y;                \
                }                                                            \
            xg += CT_ * IN_;                                                 \
        }                                                                    \
        cfence();                                                            \
    }

    // ---- XF(TT, P0, P1, HP, LP): xp = W_ih0 @ x[TT] + b0 (3-term split,
    //      all-MFMA, accumulate chain at full rate). 2 ds_read, 0 unpack. ----
#define XF(TT, P0, P1, HP, LP)                                               \
    {                                                                        \
        const uint4 bhu_ = (HP)[(TT) * tmul];                                \
        const uint4 blu_ = (LP)[(TT) * tmul];                                \
        const f16x8 BH_ = __builtin_bit_cast(f16x8, bhu_);                   \
        const f16x8 BL_ = __builtin_bit_cast(f16x8, blu_);                   \
        P0 = MFMA(axh[0], BH_, b0i[0]);                                      \
        P1 = MFMA(axh[1], BH_, b0i[1]);                                      \
        P0 = MFMA(axh[0], BL_, P0);                                          \
        P1 = MFMA(axh[1], BL_, P1);                                          \
        P0 = MFMA(axl[0], BH_, P0);                                          \
        P1 = MFMA(axl[1], BH_, P1);                                          \
    }

    // ---- STEPP(RR, Q0, Q1, DOX, HP, LP): consume xp(RR)=Q, regenerate
    //      Q = xp(RR+2) in place. h2 via full-rate MFMA accumulate chain. ----
#define STEPP(RR, Q0, Q1, DOX, HP, LP)                                       \
    {                                                                        \
        const f32x4 c0_ = MFMA(ah0[0], h1f, Q0);                             \
        const f32x4 c1_ = MFMA(ah0[1], h1f, Q1);                             \
        f32x4 d0_ = MFMA(ai1[0], h1f, b1i[0]);                               \
        f32x4 d1_ = MFMA(ai1[1], h1f, b1i[1]);                               \
        d0_ = MFMA(ah1[0], h2f, d0_);                                        \
        d1_ = MFMA(ah1[1], h2f, d1_);                                        \
        if (DOX) { XF((((RR) + 2) & 15), Q0, Q1, HP, LP) }                   \
        f16x8 nh1_, nh2_;                                                    \
        _Pragma("unroll")                                                    \
        for (int r_ = 0; r_ < 4; ++r_) {                                     \
            nh1_[r_]     = (_Float16)fmaxf(c0_[r_], 0.f);                    \
            nh1_[4 + r_] = (_Float16)fmaxf(c1_[r_], 0.f);                    \
            nh2_[r_]     = (_Float16)fmaxf(d0_[r_], 0.f);                    \
            nh2_[4 + r_] = (_Float16)fmaxf(d1_[r_], 0.f);                    \
        }                                                                    \
        h1f = nh1_; h2f = nh2_;                                              \
    }

    // ---- chunk 0: stage, fill pipeline, special step 0 (h2[-1]=0) ----
    DUMP(0, 1);                      // stage chunk 0, prefetch chunk 1
    XF(0, xpE0, xpE1, hpA, lpA);     // xp(0)
    XF(1, xpO0, xpO1, hpA, lpA);     // xp(1)
    {
        f16x8 nh1;
#pragma unroll
        for (int r = 0; r < 4; ++r) {
            nh1[r]     = (_Float16)fmaxf(xpE0[r], 0.f);
            nh1[4 + r] = (_Float16)fmaxf(xpE1[r], 0.f);
        }
        h1f = nh1;                   // h2f stays 0
        XF(2, xpE0, xpE1, hpA, lpA); // regenerate xpE = xp(2)
    }
    STEPP(1,  xpO0, xpO1, 1, hpA, lpA);
#pragma unroll
    for (int r = 2; r < 8; r += 2) {
        STEPP(r,     xpE0, xpE1, 1, hpA, lpA);
        STEPP(r + 1, xpO0, xpO1, 1, hpA, lpA);
    }
    DUMP(1, 1);                      // stage chunk 1, prefetch chunk 2
#pragma unroll
    for (int r = 8; r < 14; r += 2) {
        STEPP(r,     xpE0, xpE1, 1, hpA, lpA);
        STEPP(r + 1, xpO0, xpO1, 1, hpA, lpA);
    }
    STEPP(14, xpE0, xpE1, 1, hpB, lpB);   // xp(0) of chunk 1
    STEPP(15, xpO0, xpO1, 1, hpB, lpB);   // xp(1) of chunk 1

    // ---- chunks 1..30 (cur/nxt pointer swap) ----
    const uint4 *hpc = hpB, *lpc = lpB, *hpn = hpA, *lpn = lpA;
    int wbuf = 0;                    // buffer DUMPed this iteration (= nxt)
#pragma unroll 1
    for (int n = 1; n <= 30; ++n) {
#pragma unroll
        for (int r = 0; r < 8; r += 2) {
            STEPP(r,     xpE0, xpE1, 1, hpc, lpc);
            STEPP(r + 1, xpO0, xpO1, 1, hpc, lpc);
        }
        DUMP(wbuf, (n < 30));        // stage chunk n+1, prefetch chunk n+2
#pragma unroll
        for (int r = 8; r < 14; r += 2) {
            STEPP(r,     xpE0, xpE1, 1, hpc, lpc);
            STEPP(r + 1, xpO0, xpO1, 1, hpc, lpc);
        }
        STEPP(14, xpE0, xpE1, 1, hpn, lpn);
        STEPP(15, xpO0, xpO1, 1, hpn, lpn);
        const uint4* t1 = hpc; hpc = hpn; hpn = t1;
        const uint4* t2 = lpc; lpc = lpn; lpn = t2;
        wbuf ^= 1;
    }

    // ---- chunk 31 (no staging; steps 14/15 don't regenerate) ----
#pragma unroll
    for (int r = 0; r < 14; r += 2) {
        STEPP(r,     xpE0, xpE1, 1, hpc, lpc);
        STEPP(r + 1, xpO0, xpO1, 1, hpc, lpc);
    }
    STEPP(14, xpE0, xpE1, 0, hpc, lpc);
    STEPP(15, xpO0, xpO1, 0, hpc, lpc);

    // ---- epilogue: h2[511] = relu(b1 + W_ih1.h1[511] + W_hh1.h2[510]) ----
    {
        f32x4 d0 = MFMA(ai1[0], h1f, b1i[0]);
        f32x4 d1 = MFMA(ai1[1], h1f, b1i[1]);
        d0 = MFMA(ah1[0], h2f, d0);
        d1 = MFMA(ah1[1], h2f, d1);
        f16x8 nh2;
#pragma unroll
        for (int r = 0; r < 4; ++r) {
            nh2[r]     = (_Float16)fmaxf(d0[r], 0.f);
            nh2[4 + r] = (_Float16)fmaxf(d1[r], 0.f);
        }
        h2f = nh2;
    }

    // ---- FC head ----
#pragma unroll
    for (int r = 0; r < 4; ++r) {
        hfin[c][4 * g + r]      = h2f[r];
        hfin[c][16 + 4 * g + r] = h2f[4 + r];
    }
    cfence();   // single-wave in-order DS pipe
    {
        float acc0 = b_fc[g];
        float acc1 = b_fc[g + 4];
        float acc2 = (g == 0) ? b_fc[8] : 0.f;
#pragma unroll
        for (int k = 0; k < H_; ++k) {
            const float hv = (float)hfin[c][k];
            acc0 = fmaf(W_fc[g * H_ + k], hv, acc0);
            acc1 = fmaf(W_fc[(g + 4) * H_ + k], hv, acc1);
            if (g == 0) acc2 = fmaf(W_fc[8 * H_ + k], hv, acc2);
        }
        out[b * NC_ + g]     = acc0;
        out[b * NC_ + g + 4] = acc1;
        if (g == 0) out[b * NC_ + 8] = acc2;
    }
#undef DUMP
#undef XF
#undef STEPP
}

extern "C" void kernel_launch(void* const* d_in, const int* in_sizes, int n_in,
                              void* d_out, int out_size, void* d_ws, size_t ws_size,
                              hipStream_t stream) {
    const float* x     = (const float*)d_in[0];
    const float* W_ih0 = (const float*)d_in[1];
    const float* W_hh0 = (const float*)d_in[2];
    const float* b_ih0 = (const float*)d_in[3];
    const float* b_hh0 = (const float*)d_in[4];
    const float* W_ih1 = (const float*)d_in[5];
    const float* W_hh1 = (const float*)d_in[6];
    const float* b_ih1 = (const float*)d_in[7];
    const float* b_hh1 = (const float*)d_in[8];
    const float* W_fc  = (const float*)d_in[9];
    const float* b_fc  = (const float*)d_in[10];
    float* out = (float*)d_out;

    const int B = in_sizes[0] / (T_ * IN_);   // 4096
    gesture_rnn_kernel<<<dim3(B / 16), dim3(64), 0, stream>>>(
        x, W_ih0, W_hh0, b_ih0, b_hh0, W_ih1, W_hh1, b_ih1, b_hh1,
        W_fc, b_fc, out);
}

// Round 10
// 213.321 us; speedup vs baseline: 1.4502x; 1.0200x over previous
//
#include <hip/hip_runtime.h>

// GestureRNN v18: v17 + 2-step-ahead REGISTER prefetch of x B-fragments
// (ds_read fully decoupled from the XF MFMAs).
// B=4096, T=512, IN=10, H=32, NCLS=9.
//
// v17 post-mortem (113.8us, MfmaUtil 8.7%, VALUBusy 14.9%): VALU diet worked
// (199->114) but ~400 cyc/step stall remains. Root cause visible in source:
// XF's ds_read_b128 pair is consumed by the MFMA issued IMMEDIATELY after ->
// full LDS latency (~120-150 cyc) exposed every step, plus the MFMA->cvt->
// B-operand chain. v18 holds fragments in registers (fE/fO hi+lo), each
// PRE-loaded TWO steps before its XF consumes it (~250 cyc issue distance).
// Step = 6 rec MFMA + 6 XF MFMA (reg operands) + 2 ds_read (next parity) +
// cvt. Identical arithmetic to v17; schedule-only change.
// Layout conjugation K(k)=16*((k>>2)&1)+4*(k>>3)+(k&3) HW-verified (v12+).
// 256 blocks x 1 wave.

constexpr int T_  = 512;
constexpr int IN_ = 10;
constexpr int H_  = 32;
constexpr int NC_ = 9;
constexpr int CT_ = 16;        // timesteps per chunk
constexpr int NCH = T_ / CT_;  // 32 chunks

typedef _Float16 f16x8 __attribute__((ext_vector_type(8)));
typedef _Float16 h2t  __attribute__((ext_vector_type(2)));
typedef float    f32x4 __attribute__((ext_vector_type(4)));

__device__ __forceinline__ void cfence() { __asm__ volatile("" ::: "memory"); }

__device__ __forceinline__ f32x4 MFMA(f16x8 a, f16x8 b, f32x4 c) {
    return __builtin_amdgcn_mfma_f32_16x16x32_f16(a, b, c, 0, 0, 0);
}

__global__ __launch_bounds__(64, 1)
__attribute__((amdgpu_waves_per_eu(1, 1)))
void gesture_rnn_kernel(
    const float* __restrict__ x,      // [B, T, IN]
    const float* __restrict__ W_ih0,  // [H, IN]
    const float* __restrict__ W_hh0,  // [H, H]
    const float* __restrict__ b_ih0,  // [H]
    const float* __restrict__ b_hh0,  // [H]
    const float* __restrict__ W_ih1,  // [H, H]
    const float* __restrict__ W_hh1,  // [H, H]
    const float* __restrict__ b_ih1,  // [H]
    const float* __restrict__ b_hh1,  // [H]
    const float* __restrict__ W_fc,   // [NC, H]
    const float* __restrict__ b_fc,   // [NC]
    float* __restrict__ out)          // [B, NC]
{
    const int lane = threadIdx.x;     // 0..63
    const int c    = lane & 15;       // batch col (B/C col, A row)
    const int g    = lane >> 4;       // k-group: holds k = 8g..8g+7
    const long b   = (long)blockIdx.x * 16 + c;

    // ---- A-fragments (k-order K(k) for recurrent mats; natural for xproj) --
    f16x8 ah0[2], ai1[2], ah1[2], axh[2], axl[2];
#pragma unroll
    for (int Tt = 0; Tt < 2; ++Tt) {
#pragma unroll
        for (int j = 0; j < 8; ++j) {
            const int k   = 8 * g + j;
            const int kp  = 16 * ((k >> 2) & 1) + 4 * (k >> 3) + (k & 3);
            const int row = 16 * Tt + c;
            ah0[Tt][j] = (_Float16)W_hh0[row * H_ + kp];
            ai1[Tt][j] = (_Float16)W_ih1[row * H_ + kp];
            ah1[Tt][j] = (_Float16)W_hh1[row * H_ + kp];
            const float wx = (k < IN_) ? W_ih0[row * IN_ + k] : 0.f;
            const _Float16 wh = (_Float16)wx;
            axh[Tt][j] = wh;
            axl[Tt][j] = (_Float16)(wx - (float)wh);
        }
    }
    f32x4 b0i[2], b1i[2];
#pragma unroll
    for (int Tt = 0; Tt < 2; ++Tt)
#pragma unroll
        for (int r = 0; r < 4; ++r) {
            const int uu = 16 * Tt + 4 * g + r;
            b0i[Tt][r] = b_ih0[uu] + b_hh0[uu];
            b1i[Tt][r] = b_ih1[uu] + b_hh1[uu];
        }

    // ---- LDS: packed-f16 x B-fragments, double-buffered ----
    __shared__ uint4 xhl[2][2][CT_][2][16];  // [buf][hi/lo][t][g01][c]
    __shared__ uint4 zs4;                    // zero frag for g>=2 lanes
    __shared__ _Float16 hfin[16][H_];

    if (lane == 0) zs4 = make_uint4(0u, 0u, 0u, 0u);

    // ---- x load: lane(g,c) owns timesteps 4g+s (s=0..3) of batch b ----
    float xr[4][IN_];
    const float* xg = x + ((size_t)b * T_ + 4 * g) * IN_;
#pragma unroll
    for (int s = 0; s < 4; ++s)
#pragma unroll
        for (int i = 0; i < IN_; i += 2) {
            const float2 v = *(const float2*)(xg + s * IN_ + i);
            xr[s][i] = v.x; xr[s][i + 1] = v.y;
        }
    xg += CT_ * IN_;

    // per-lane read pointers: g<2 reads its fragment slice, g>=2 the zero slot
    const int tmul = (g < 2) ? 32 : 0;       // uint4 stride per t
    const uint4* hpA = (g < 2) ? &xhl[0][0][0][g][c] : &zs4;
    const uint4* lpA = (g < 2) ? &xhl[0][1][0][g][c] : &zs4;
    const uint4* hpB = (g < 2) ? &xhl[1][0][0][g][c] : &zs4;
    const uint4* lpB = (g < 2) ? &xhl[1][1][0][g][c] : &zs4;

    f16x8 h1f, h2f;
#pragma unroll
    for (int j = 0; j < 8; ++j) { h1f[j] = (_Float16)0.f; h2f[j] = (_Float16)0.f; }

    f32x4 xpE0, xpE1, xpO0, xpO1;   // parity-held xp pipeline
    uint4 fEh, fEl, fOh, fOl;       // parity-held fragment prefetch regs

    // ---- DUMP(BUF, PREFETCH): convert xr -> packed f16 hi/lo frags in LDS --
#define DUMP(BUF, PREFETCH)                                                  \
    {                                                                        \
        _Pragma("unroll")                                                    \
        for (int s_ = 0; s_ < 4; ++s_) {                                     \
            const int t_ = 4 * g + s_;                                       \
            unsigned int hd_[5], ld_[5];                                     \
            _Pragma("unroll")                                                \
            for (int p_ = 0; p_ < 5; ++p_) {                                 \
                const float a_ = xr[s_][2 * p_], q_ = xr[s_][2 * p_ + 1];    \
                const _Float16 ha_ = (_Float16)a_, hb_ = (_Float16)q_;       \
                h2t hh_; hh_[0] = ha_; hh_[1] = hb_;                         \
                hd_[p_] = __builtin_bit_cast(unsigned int, hh_);             \
                h2t ll_; ll_[0] = (_Float16)(a_ - (float)ha_);               \
                ll_[1] = (_Float16)(q_ - (float)hb_);                        \
                ld_[p_] = __builtin_bit_cast(unsigned int, ll_);             \
            }                                                                \
            xhl[BUF][0][t_][0][c] = make_uint4(hd_[0], hd_[1], hd_[2], hd_[3]); \
            xhl[BUF][0][t_][1][c] = make_uint4(hd_[4], 0u, 0u, 0u);          \
            xhl[BUF][1][t_][0][c] = make_uint4(ld_[0], ld_[1], ld_[2], ld_[3]); \
            xhl[BUF][1][t_][1][c] = make_uint4(ld_[4], 0u, 0u, 0u);          \
        }                                                                    \
        if (PREFETCH) {                                                      \
            _Pragma("unroll")                                                \
            for (int s_ = 0; s_ < 4; ++s_)                                   \
                _Pragma("unroll")                                            \
                for (int i_ = 0; i_ < IN_; i_ += 2) {                        \
                    const float2 v_ = *(const float2*)(xg + s_ * IN_ + i_);  \
                    xr[s_][i_] = v_.x; xr[s_][i_ + 1] = v_.y;                \
                }                                                            \
            xg += CT_ * IN_;                                                 \
        }                                                                    \
        cfence();                                                            \
    }

    // ---- PRE: ds_read fragment t=TT into regs (consumed 2 steps later) ----
#define PRE(TT, FH, FL, HP, LP)                                              \
    { FH = (HP)[(TT) * tmul]; FL = (LP)[(TT) * tmul]; }

    // ---- XFR: xp = W_ih0 @ x + b0 from REGISTER fragments (6 MFMA) ----
#define XFR(FH, FL, P0, P1)                                                  \
    {                                                                        \
        const f16x8 BH_ = __builtin_bit_cast(f16x8, FH);                     \
        const f16x8 BL_ = __builtin_bit_cast(f16x8, FL);                     \
        P0 = MFMA(axh[0], BH_, b0i[0]);                                      \
        P1 = MFMA(axh[1], BH_, b0i[1]);                                      \
        P0 = MFMA(axh[0], BL_, P0);                                          \
        P1 = MFMA(axh[1], BL_, P1);                                          \
        P0 = MFMA(axl[0], BH_, P0);                                          \
        P1 = MFMA(axl[1], BH_, P1);                                          \
    }

    // ---- STEPP: consume xp parity Q; regen Q from frag parity F (DOX);
    //      PRE next frag for this parity (DOP) from PHP/PLP at t=PT. ----
#define STEPP(Q0, Q1, FH, FL, DOX, DOP, PT, PHP, PLP)                        \
    {                                                                        \
        const f32x4 c0_ = MFMA(ah0[0], h1f, Q0);                             \
        const f32x4 c1_ = MFMA(ah0[1], h1f, Q1);                             \
        f32x4 d0_ = MFMA(ai1[0], h1f, b1i[0]);                               \
        f32x4 d1_ = MFMA(ai1[1], h1f, b1i[1]);                               \
        d0_ = MFMA(ah1[0], h2f, d0_);                                        \
        d1_ = MFMA(ah1[1], h2f, d1_);                                        \
        if (DOX) { XFR(FH, FL, Q0, Q1) }                                     \
        if (DOP) { PRE(PT, FH, FL, PHP, PLP) }                               \
        f16x8 nh1_, nh2_;                                                    \
        _Pragma("unroll")                                                    \
        for (int r_ = 0; r_ < 4; ++r_) {                                     \
            nh1_[r_]     = (_Float16)fmaxf(c0_[r_], 0.f);                    \
            nh1_[4 + r_] = (_Float16)fmaxf(c1_[r_], 0.f);                    \
            nh2_[r_]     = (_Float16)fmaxf(d0_[r_], 0.f);                    \
            nh2_[4 + r_] = (_Float16)fmaxf(d1_[r_], 0.f);                    \
        }                                                                    \
        h1f = nh1_; h2f = nh2_;                                              \
    }

    // ---- chunk 0 prologue: stage, compute xp(0)/xp(1), prime frag regs ----
    DUMP(0, 1);                          // stage chunk 0, prefetch chunk 1
    PRE(0, fEh, fEl, hpA, lpA);
    XFR(fEh, fEl, xpE0, xpE1);           // xp(0)  (prologue: stall OK)
    PRE(1, fOh, fOl, hpA, lpA);
    XFR(fOh, fOl, xpO0, xpO1);           // xp(1)
    PRE(2, fEh, fEl, hpA, lpA);          // prime parity-E frag (t=2)
    PRE(3, fOh, fOl, hpA, lpA);          // prime parity-O frag (t=3)
    {
        // special step 0: h1[0] = relu(xp(0)); h2[-1] = 0
        f16x8 nh1;
#pragma unroll
        for (int r = 0; r < 4; ++r) {
            nh1[r]     = (_Float16)fmaxf(xpE0[r], 0.f);
            nh1[4 + r] = (_Float16)fmaxf(xpE1[r], 0.f);
        }
        h1f = nh1;                       // h2f stays 0
        XFR(fEh, fEl, xpE0, xpE1);       // regen xpE = xp(2)
        PRE(4, fEh, fEl, hpA, lpA);
    }
    STEPP(xpO0, xpO1, fOh, fOl, 1, 1, 5, hpA, lpA);          // r=1
#pragma unroll
    for (int r = 2; r < 8; r += 2) {
        STEPP(xpE0, xpE1, fEh, fEl, 1, 1, r + 4, hpA, lpA);
        STEPP(xpO0, xpO1, fOh, fOl, 1, 1, r + 5, hpA, lpA);
    }
    DUMP(1, 1);                          // stage chunk 1, prefetch chunk 2
#pragma unroll
    for (int r = 8; r < 12; r += 2) {
        STEPP(xpE0, xpE1, fEh, fEl, 1, 1, r + 4, hpA, lpA);
        STEPP(xpO0, xpO1, fOh, fOl, 1, 1, r + 5, hpA, lpA);
    }
    STEPP(xpE0, xpE1, fEh, fEl, 1, 1, 0, hpB, lpB);          // r=12
    STEPP(xpO0, xpO1, fOh, fOl, 1, 1, 1, hpB, lpB);          // r=13
    STEPP(xpE0, xpE1, fEh, fEl, 1, 1, 2, hpB, lpB);          // r=14
    STEPP(xpO0, xpO1, fOh, fOl, 1, 1, 3, hpB, lpB);          // r=15

    // ---- chunks 1..30 ----
    const uint4 *hpc = hpB, *lpc = lpB, *hpn = hpA, *lpn = lpA;
    int wbuf = 0;                        // buffer DUMPed this iteration (=nxt)
#pragma unroll 1
    for (int n = 1; n <= 30; ++n) {
#pragma unroll
        for (int r = 0; r < 8; r += 2) {
            STEPP(xpE0, xpE1, fEh, fEl, 1, 1, r + 4, hpc, lpc);
            STEPP(xpO0, xpO1, fOh, fOl, 1, 1, r + 5, hpc, lpc);
        }
        DUMP(wbuf, (n < 30));            // stage chunk n+1, prefetch n+2
#pragma unroll
        for (int r = 8; r < 12; r += 2) {
            STEPP(xpE0, xpE1, fEh, fEl, 1, 1, r + 4, hpc, lpc);
            STEPP(xpO0, xpO1, fOh, fOl, 1, 1, r + 5, hpc, lpc);
        }
        STEPP(xpE0, xpE1, fEh, fEl, 1, 1, 0, hpn, lpn);      // r=12
        STEPP(xpO0, xpO1, fOh, fOl, 1, 1, 1, hpn, lpn);      // r=13
        STEPP(xpE0, xpE1, fEh, fEl, 1, 1, 2, hpn, lpn);      // r=14
        STEPP(xpO0, xpO1, fOh, fOl, 1, 1, 3, hpn, lpn);      // r=15
        const uint4* t1 = hpc; hpc = hpn; hpn = t1;
        const uint4* t2 = lpc; lpc = lpn; lpn = t2;
        wbuf ^= 1;
    }

    // ---- chunk 31 (no staging; r>=12 no PRE; r>=14 no XFR) ----
#pragma unroll
    for (int r = 0; r < 12; r += 2) {
        STEPP(xpE0, xpE1, fEh, fEl, 1, 1, r + 4, hpc, lpc);
        STEPP(xpO0, xpO1, fOh, fOl, 1, 1, r + 5, hpc, lpc);
    }
    STEPP(xpE0, xpE1, fEh, fEl, 1, 0, 0, hpc, lpc);          // r=12 (xp14)
    STEPP(xpO0, xpO1, fOh, fOl, 1, 0, 0, hpc, lpc);          // r=13 (xp15)
    STEPP(xpE0, xpE1, fEh, fEl, 0, 0, 0, hpc, lpc);          // r=14
    STEPP(xpO0, xpO1, fOh, fOl, 0, 0, 0, hpc, lpc);          // r=15

    // ---- epilogue: h2[511] = relu(b1 + W_ih1.h1[511] + W_hh1.h2[510]) ----
    {
        f32x4 d0 = MFMA(ai1[0], h1f, b1i[0]);
        f32x4 d1 = MFMA(ai1[1], h1f, b1i[1]);
        d0 = MFMA(ah1[0], h2f, d0);
        d1 = MFMA(ah1[1], h2f, d1);
        f16x8 nh2;
#pragma unroll
        for (int r = 0; r < 4; ++r) {
            nh2[r]     = (_Float16)fmaxf(d0[r], 0.f);
            nh2[4 + r] = (_Float16)fmaxf(d1[r], 0.f);
        }
        h2f = nh2;
    }

    // ---- FC head ----
#pragma unroll
    for (int r = 0; r < 4; ++r) {
        hfin[c][4 * g + r]      = h2f[r];
        hfin[c][16 + 4 * g + r] = h2f[4 + r];
    }
    cfence();   // single-wave in-order DS pipe
    {
        float acc0 = b_fc[g];
        float acc1 = b_fc[g + 4];
        float acc2 = (g == 0) ? b_fc[8] : 0.f;
#pragma unroll
        for (int k = 0; k < H_; ++k) {
            const float hv = (float)hfin[c][k];
            acc0 = fmaf(W_fc[g * H_ + k], hv, acc0);
            acc1 = fmaf(W_fc[(g + 4) * H_ + k], hv, acc1);
            if (g == 0) acc2 = fmaf(W_fc[8 * H_ + k], hv, acc2);
        }
        out[b * NC_ + g]     = acc0;
        out[b * NC_ + g + 4] = acc1;
        if (g == 0) out[b * NC_ + 8] = acc2;
    }
#undef DUMP
#undef PRE
#undef XFR
#undef STEPP
}

extern "C" void kernel_launch(void* const* d_in, const int* in_sizes, int n_in,
                              void* d_out, int out_size, void* d_ws, size_t ws_size,
                              hipStream_t stream) {
    const float* x     = (const float*)d_in[0];
    const float* W_ih0 = (const float*)d_in[1];
    const float* W_hh0 = (const float*)d_in[2];
    const float* b_ih0 = (const float*)d_in[3];
    const float* b_hh0 = (const float*)d_in[4];
    const float* W_ih1 = (const float*)d_in[5];
    const float* W_hh1 = (const float*)d_in[6];
    const float* b_ih1 = (const float*)d_in[7];
    const float* b_hh1 = (const float*)d_in[8];
    const float* W_fc  = (const float*)d_in[9];
    const float* b_fc  = (const float*)d_in[10];
    float* out = (float*)d_out;

    const int B = in_sizes[0] / (T_ * IN_);   // 4096
    gesture_rnn_kernel<<<dim3(B / 16), dim3(64), 0, stream>>>(
        x, W_ih0, W_hh0, b_ih0, b_hh0, W_ih1, W_hh1, b_ih1, b_hh1,
        W_fc, b_fc, out);
}